// Round 5
// baseline (18710.493 us; speedup 1.0000x reference)
//
#include <hip/hip_runtime.h>
#include <math.h>

// ---------------------------------------------------------------------------
// Round 5 == round 4 resubmit (round 4 never ran: GPU acquisition timeout).
// Fused decode, 16 waves/CU (1024 thr x 256 blocks, 1 block/CU).
//  * Merge-free flash: wave=(bb, head-pair); each 32-lane half owns one head
//    (compat 5-shuffle reduce, per-lane online softmax, PV reuses compat
//    E-registers -> E read ONCE per flash). No LDS scratch, no merges.
//  * Ws(K=512) GEMV removed: qfirst/qprev incrementally maintained
//    (qprev = E[sel]@Ws_bot after each selection; qfirst once at step 0).
//  * GEMVs: 4-way K-split x 4 bb, weight f4 loaded once/block/step,
//    activation scalar broadcast from LDS, 4-way partial combine.
//  * Select: 4 waves per bb, 4 rows in flight, 6-shuffle dots.
// ---------------------------------------------------------------------------

#define BB 1024
#define NN 128
#define DD 256
#define HH 8

__device__ __forceinline__ float4 f4z() { return make_float4(0.f, 0.f, 0.f, 0.f); }
__device__ __forceinline__ float4 f4fma(float4 a, float4 b, float4 c) {
  c.x = fmaf(a.x, b.x, c.x); c.y = fmaf(a.y, b.y, c.y);
  c.z = fmaf(a.z, b.z, c.z); c.w = fmaf(a.w, b.w, c.w); return c;
}
__device__ __forceinline__ float4 svfma(float s, float4 w, float4 c) {
  c.x = fmaf(s, w.x, c.x); c.y = fmaf(s, w.y, c.y);
  c.z = fmaf(s, w.z, c.z); c.w = fmaf(s, w.w, c.w); return c;
}
__device__ __forceinline__ float4 f4scale(float4 a, float s) {
  a.x *= s; a.y *= s; a.z *= s; a.w *= s; return a;
}

// ---------------- precompute kernels ----------------
__global__ void k_mean(const float* __restrict__ E, float* __restrict__ g0) {
  int b = blockIdx.x, t = threadIdx.x;
  const float* e = E + (size_t)b * NN * DD + t;
  float s = 0.f;
#pragma unroll 8
  for (int n = 0; n < NN; ++n) s += e[n * DD];
  g0[b * DD + t] = s * (1.f / 128.f);
}

__global__ void k_transpose(const float* __restrict__ A, float* __restrict__ AT) {
  __shared__ float tile[32][33];
  int bi = blockIdx.x & 7, bo = blockIdx.x >> 3;
  int tx = threadIdx.x & 31, ty = threadIdx.x >> 5;
  for (int j = 0; j < 32; j += 8)
    tile[ty + j][tx] = A[(size_t)(bi * 32 + ty + j) * DD + bo * 32 + tx];
  __syncthreads();
  for (int j = 0; j < 32; j += 8)
    AT[(size_t)(bo * 32 + ty + j) * DD + bi * 32 + tx] = tile[tx][ty + j];
}

__global__ __launch_bounds__(256) void k_gemm(const float* __restrict__ A,
                                              const float* __restrict__ Bm,
                                              float* __restrict__ C,
                                              int M, int Nn, int K, int transB) {
  __shared__ float As[32][33], Bs[32][33];
  int tn = blockIdx.x, tm = blockIdx.y;
  int t = threadIdx.x;
  int c = t & 31, r4 = t >> 5;
  float acc[4] = {0.f, 0.f, 0.f, 0.f};
  for (int k0 = 0; k0 < K; k0 += 32) {
#pragma unroll
    for (int i = 0; i < 4; ++i) {
      int li = t + i * 256; int ar = li >> 5, ac = li & 31;
      As[ar][ac] = A[(size_t)(tm * 32 + ar) * K + k0 + ac];
    }
    if (!transB) {
#pragma unroll
      for (int i = 0; i < 4; ++i) {
        int li = t + i * 256; int kk = li >> 5, cc = li & 31;
        Bs[kk][cc] = Bm[(size_t)(k0 + kk) * Nn + tn * 32 + cc];
      }
    } else {
#pragma unroll
      for (int i = 0; i < 4; ++i) {
        int li = t + i * 256; int cc = li >> 5, kk = li & 31;
        Bs[kk][cc] = Bm[(size_t)(tn * 32 + cc) * K + k0 + kk];
      }
    }
    __syncthreads();
#pragma unroll
    for (int kk = 0; kk < 32; ++kk) {
      float bv = Bs[kk][c];
#pragma unroll
      for (int i = 0; i < 4; ++i) acc[i] += As[r4 + i * 8][kk] * bv;
    }
    __syncthreads();
  }
#pragma unroll
  for (int i = 0; i < 4; ++i)
    C[(size_t)(tm * 32 + r4 + i * 8) * Nn + tn * 32 + c] = acc[i];
}

// qws0 = Wph @ Ws  (step-0 context projection)
__global__ void k_qws0(const float* __restrict__ Wph, const float* __restrict__ Ws,
                       float* __restrict__ qws0) {
  int c = threadIdx.x;
  float s = 0.f;
  for (int k = 0; k < 512; ++k) s += Wph[k] * Ws[(size_t)k * DD + c];
  qws0[c] = s;
}

// ---------------- fused decode ----------------
__global__ __launch_bounds__(1024) void k_decode(
    const float* __restrict__ E, const float* __restrict__ coords,
    const float* __restrict__ Ws, const float* __restrict__ W1,
    const float* __restrict__ b1, const float* __restrict__ W2,
    const float* __restrict__ b2, const float* __restrict__ WkT,
    const float* __restrict__ Wv, const float* __restrict__ M1,
    const float* __restrict__ M2, const float* __restrict__ qws0,
    const float* __restrict__ qlin0, float* __restrict__ out) {
  __shared__ float qlinS[4][256];   // persistent glimpse@Wc
  __shared__ float gl2S[4][256];
  __shared__ float qS[4][256];      // q; reused as e_sel in phase N
  __shared__ float hS[4][256];
  __shared__ float q2S[4][256];
  __shared__ float headsS[4][256];
  __shared__ float qfS[4][256];     // E[first]@Ws_top (persistent)
  __shared__ float qpS[4][256];     // E[prev]@Ws_bot (persistent)
  __shared__ float P1[4096];        // 4-way K-split partials
  __shared__ float P2[4096];
  __shared__ float qkS[8320];       // [4bb][8h][260]
  __shared__ float hEnS[8320];      // [4bb][8h][260]
  __shared__ int   lstS[4][128];
  __shared__ float logitS[4][128];
  __shared__ unsigned visS[4][4];
  __shared__ int   selS[4];
  __shared__ float stS[4][6];       // ll, cost, fx, fy, px, py

  const int t = threadIdx.x;
  const int w = t >> 6, l = t & 63;
  const int blk = blockIdx.x;
  const int gbb = w & 3;            // batch row within block
  const int gks = w >> 2;           // K-quarter / head-pair / row-phase role
  const int c0 = l * 4;
  const int cbb = t >> 8, cc = t & 255;  // combine roles (1 output/thread)

  // ---- init ----
  qlinS[cbb][cc] = qlin0[(size_t)(blk * 4 + cbb) * DD + cc];
  if (t < 16) visS[t >> 2][t & 3] = 0u;
  if (t < 4) {
#pragma unroll
    for (int j = 0; j < 6; ++j) stS[t][j] = 0.f;
  }
  __syncthreads();

  for (int step = 0; step < NN; ++step) {
    const int cnt = NN - step;

    // ===== A: q assemble + unvisited list =====
    {
      float q = qlinS[cbb][cc];
      q += (step == 0) ? qws0[cc] : (qfS[cbb][cc] + qpS[cbb][cc]);
      qS[cbb][cc] = q;
    }
    if (t < 512) {
      int bb = t >> 7, n = t & 127;
      unsigned wd = visS[bb][n >> 5];
      bool unv = !((wd >> (n & 31)) & 1u);
      unsigned long long m = __ballot(unv);
      int rank = __popcll(m & ((1ull << l) - 1ull));
      int half = (t >> 6) & 1;
      int base2 = half ? (__popc(~visS[bb][0]) + __popc(~visS[bb][1])) : 0;
      if (unv) lstS[bb][base2 + rank] = n;
    }
    __syncthreads();

    // ===== B: h_pre = q @ W1  (K-split) =====
    {
      float4 acc = f4z();
      const float* wp = W1 + (size_t)(gks * 64) * DD + c0;
      const float* xr = &qS[gbb][gks * 64];
#pragma unroll 8
      for (int k = 0; k < 64; ++k) {
        float4 wv = *(const float4*)wp; wp += DD;
        acc = svfma(xr[k], wv, acc);
      }
      *(float4*)&P1[(gks * 4 + gbb) * 256 + c0] = acc;
    }
    __syncthreads();
    // ===== C: h = relu(.+b1) =====
    {
      float s = b1[cc];
#pragma unroll
      for (int ks = 0; ks < 4; ++ks) s += P1[(ks * 4 + cbb) * 256 + cc];
      hS[cbb][cc] = fmaxf(s, 0.f);
    }
    __syncthreads();

    // ===== D: h @ W2 =====
    {
      float4 acc = f4z();
      const float* wp = W2 + (size_t)(gks * 64) * DD + c0;
      const float* xr = &hS[gbb][gks * 64];
#pragma unroll 8
      for (int k = 0; k < 64; ++k) {
        float4 wv = *(const float4*)wp; wp += DD;
        acc = svfma(xr[k], wv, acc);
      }
      *(float4*)&P1[(gks * 4 + gbb) * 256 + c0] = acc;
    }
    __syncthreads();
    // ===== E: q2 = q + . + b2 =====
    {
      float s = qS[cbb][cc] + b2[cc];
#pragma unroll
      for (int ks = 0; ks < 4; ++ks) s += P1[(ks * 4 + cbb) * 256 + cc];
      q2S[cbb][cc] = s;
    }
    __syncthreads();

    // ===== F: qk[h] = q2-strip @ WkT-strip (block-diag K=32) =====
    {
#pragma unroll
      for (int hh = 0; hh < 2; ++hh) {
        int h = gks * 2 + hh;
        float4 acc = f4z();
        const float* wp = WkT + (size_t)(h * 32) * DD + c0;
        const float* xr = &q2S[gbb][h * 32];
#pragma unroll 8
        for (int k = 0; k < 32; ++k) {
          float4 wv = *(const float4*)wp; wp += DD;
          acc = svfma(xr[k], wv, acc);
        }
        *(float4*)&qkS[(gbb * 8 + h) * 260 + c0] = acc;
      }
    }
    __syncthreads();

    // ===== G: flash (merge-free; half-wave owns one head) =====
    {
      const int hsel = l >> 5, s32 = l & 31;
      const int fh = gks * 2 + hsel;
      const float* qkp = &qkS[(gbb * 8 + fh) * 260 + s32 * 8];
      float4 qr0 = *(const float4*)qkp, qr1 = *(const float4*)(qkp + 4);
      const float* Eb = E + (size_t)(blk * 4 + gbb) * (NN * DD);
      float4 hE0 = f4z(), hE1 = f4z();
      float m_run = -INFINITY, l_run = 0.f;

      for (int base = 0; base < cnt; base += 4) {
        float4 e0[4], e1[4];
        float pc[4];
#pragma unroll
        for (int r = 0; r < 4; ++r) {
          int idx = base + r;
          int ridx = (idx < cnt) ? idx : (cnt - 1);
          int row = lstS[gbb][ridx];
          const float* ep = Eb + row * DD + s32 * 8;
          e0[r] = *(const float4*)ep;
          e1[r] = *(const float4*)(ep + 4);
        }
#pragma unroll
        for (int r = 0; r < 4; ++r) {
          float4 a = f4fma(e0[r], qr0, f4z());
          a = f4fma(e1[r], qr1, a);
          float s = (a.x + a.y) + (a.z + a.w);
          s += __shfl_xor(s, 1);
          s += __shfl_xor(s, 2);
          s += __shfl_xor(s, 4);
          s += __shfl_xor(s, 8);
          s += __shfl_xor(s, 16);
          pc[r] = (base + r < cnt) ? s * 0.17677669529663687f : -INFINITY;
        }
        float mt = fmaxf(fmaxf(pc[0], pc[1]), fmaxf(pc[2], pc[3]));
        float newm = fmaxf(m_run, mt);
        float alpha = expf(m_run - newm);
        float psum = 0.f;
#pragma unroll
        for (int r = 0; r < 4; ++r) { pc[r] = expf(pc[r] - newm); psum += pc[r]; }
        l_run = l_run * alpha + psum;
        m_run = newm;
        hE0 = f4scale(hE0, alpha); hE1 = f4scale(hE1, alpha);
#pragma unroll
        for (int r = 0; r < 4; ++r) {
          hE0 = svfma(pc[r], e0[r], hE0);
          hE1 = svfma(pc[r], e1[r], hE1);
        }
      }
      float inv = 1.f / l_run;
      float* op = &hEnS[(gbb * 8 + fh) * 260 + s32 * 8];
      *(float4*)op = f4scale(hE0, inv);
      *(float4*)(op + 4) = f4scale(hE1, inv);
    }
    __syncthreads();

    // ===== H: heads = hEn @ Wv strips =====
    {
      int hh = l >> 3;  // head of output col c0
      const float* hrow = &hEnS[(gbb * 8 + hh) * 260 + gks * 64];
      float4 acc = f4z();
      const float* wp = Wv + (size_t)(gks * 64) * DD + c0;
#pragma unroll 8
      for (int k = 0; k < 64; ++k) {
        float4 wv = *(const float4*)wp; wp += DD;
        acc = svfma(hrow[k], wv, acc);
      }
      *(float4*)&P1[(gks * 4 + gbb) * 256 + c0] = acc;
    }
    __syncthreads();
    // ===== I: heads combine =====
    {
      float s = 0.f;
#pragma unroll
      for (int ks = 0; ks < 4; ++ks) s += P1[(ks * 4 + cbb) * 256 + cc];
      headsS[cbb][cc] = s;
    }
    __syncthreads();

    // ===== J: qlin' = heads@M1 ; gl2 = heads@M2 =====
    {
      float4 a1 = f4z(), a2 = f4z();
      const float* p1p = M1 + (size_t)(gks * 64) * DD + c0;
      const float* p2p = M2 + (size_t)(gks * 64) * DD + c0;
      const float* xr = &headsS[gbb][gks * 64];
#pragma unroll 4
      for (int k = 0; k < 64; ++k) {
        float s = xr[k];
        float4 w1v = *(const float4*)p1p; p1p += DD;
        float4 w2v = *(const float4*)p2p; p2p += DD;
        a1 = svfma(s, w1v, a1);
        a2 = svfma(s, w2v, a2);
      }
      *(float4*)&P1[(gks * 4 + gbb) * 256 + c0] = a1;
      *(float4*)&P2[(gks * 4 + gbb) * 256 + c0] = a2;
    }
    __syncthreads();
    // ===== K: combine =====
    {
      float s1 = 0.f, s2 = 0.f;
#pragma unroll
      for (int ks = 0; ks < 4; ++ks) {
        s1 += P1[(ks * 4 + cbb) * 256 + cc];
        s2 += P2[(ks * 4 + cbb) * 256 + cc];
      }
      qlinS[cbb][cc] = s1;
      gl2S[cbb][cc] = s2;
    }
    __syncthreads();

    // ===== L: pointer logits over unvisited =====
    {
      const float* Eb = E + (size_t)(blk * 4 + gbb) * (NN * DD);
      float4 gv = *(const float4*)&gl2S[gbb][c0];
      for (int base = gks; base < cnt; base += 16) {
        float sres[4];
#pragma unroll
        for (int j = 0; j < 4; ++j) {
          int idx = base + j * 4;
          int row = lstS[gbb][(idx < cnt) ? idx : 0];
          float4 ev = *(const float4*)(Eb + row * DD + c0);
          float4 a = f4fma(ev, gv, f4z());
          sres[j] = (a.x + a.y) + (a.z + a.w);
        }
#pragma unroll
        for (int j = 0; j < 4; ++j) {
          float s = sres[j];
          s += __shfl_xor(s, 1);
          s += __shfl_xor(s, 2);
          s += __shfl_xor(s, 4);
          s += __shfl_xor(s, 8);
          s += __shfl_xor(s, 16);
          s += __shfl_xor(s, 32);
          int idx = base + j * 4;
          if (l == 0 && idx < cnt) logitS[gbb][idx] = 10.f * tanhf(s * 0.0625f);
        }
      }
    }
    __syncthreads();

    // ===== M: argmax (first-index ties) + sumexp + state update =====
    if (w < 4) {
      int bb = w;
      float v0 = (l < cnt) ? logitS[bb][l] : -INFINITY;
      float v1 = (l + 64 < cnt) ? logitS[bb][l + 64] : -INFINITY;
      float bv; int bi;
      if (v1 > v0) { bv = v1; bi = l + 64; } else { bv = v0; bi = l; }
#pragma unroll
      for (int off = 32; off >= 1; off >>= 1) {
        float ov = __shfl_xor(bv, off);
        int oi = __shfl_xor(bi, off);
        if (ov > bv || (ov == bv && oi < bi)) { bv = ov; bi = oi; }
      }
      float p0 = (l < cnt) ? expf(v0 - bv) : 0.f;
      float p1 = (l + 64 < cnt) ? expf(v1 - bv) : 0.f;
      float s = p0 + p1;
#pragma unroll
      for (int off = 32; off >= 1; off >>= 1) s += __shfl_xor(s, off);
      if (l == 0) {
        int sel = lstS[bb][bi];
        float logp = -logf(s);
        visS[bb][sel >> 5] |= (1u << (sel & 31));
        selS[bb] = sel;
        int gb = blk * 4 + bb;
        float cx = coords[(size_t)gb * (NN * 2) + sel * 2];
        float cy = coords[(size_t)gb * (NN * 2) + sel * 2 + 1];
        stS[bb][0] += logp;
        if (step == 0) {
          stS[bb][2] = cx; stS[bb][3] = cy;
        } else {
          float dx = stS[bb][4] - cx, dy = stS[bb][5] - cy;
          stS[bb][1] += sqrtf(dx * dx + dy * dy);
        }
        stS[bb][4] = cx; stS[bb][5] = cy;
        if (step == NN - 1) {
          float dx = cx - stS[bb][2], dy = cy - stS[bb][3];
          out[gb] = stS[bb][1] + sqrtf(dx * dx + dy * dy);
          out[BB + gb] = stS[bb][0];
        }
      }
    }
    __syncthreads();

    // ===== N: qprev = E[sel]@Ws_bot (and qfirst at step 0) =====
    if (step + 1 < NN) {
      qS[cbb][cc] = E[(size_t)(blk * 4 + cbb) * (NN * DD) +
                      (size_t)selS[cbb] * DD + cc];
      __syncthreads();
      {
        float4 acc = f4z();
        const float* wp = Ws + (size_t)(256 + gks * 64) * DD + c0;
        const float* xr = &qS[gbb][gks * 64];
#pragma unroll 8
        for (int k = 0; k < 64; ++k) {
          float4 wv = *(const float4*)wp; wp += DD;
          acc = svfma(xr[k], wv, acc);
        }
        *(float4*)&P1[(gks * 4 + gbb) * 256 + c0] = acc;
        if (step == 0) {
          float4 accF = f4z();
          const float* wpF = Ws + (size_t)(gks * 64) * DD + c0;
#pragma unroll 8
          for (int k = 0; k < 64; ++k) {
            float4 wv = *(const float4*)wpF; wpF += DD;
            accF = svfma(xr[k], wv, accF);
          }
          *(float4*)&P2[(gks * 4 + gbb) * 256 + c0] = accF;
        }
      }
      __syncthreads();
      {
        float s = 0.f;
#pragma unroll
        for (int ks = 0; ks < 4; ++ks) s += P1[(ks * 4 + cbb) * 256 + cc];
        qpS[cbb][cc] = s;
        if (step == 0) {
          float sf = 0.f;
#pragma unroll
          for (int ks = 0; ks < 4; ++ks) sf += P2[(ks * 4 + cbb) * 256 + cc];
          qfS[cbb][cc] = sf;
        }
      }
      __syncthreads();
    }
  }
}

// ---------------------------------------------------------------------------
extern "C" void kernel_launch(void* const* d_in, const int* in_sizes, int n_in,
                              void* d_out, int out_size, void* d_ws, size_t ws_size,
                              hipStream_t stream) {
  const float* coords = (const float*)d_in[0];
  const float* E      = (const float*)d_in[1];
  const float* Wk     = (const float*)d_in[2];
  const float* Wv     = (const float*)d_in[3];
  const float* Wlk    = (const float*)d_in[4];
  const float* Wo     = (const float*)d_in[5];
  const float* Wc     = (const float*)d_in[6];
  const float* Ws     = (const float*)d_in[7];
  const float* Wph    = (const float*)d_in[8];
  const float* W1     = (const float*)d_in[9];
  const float* b1     = (const float*)d_in[10];
  const float* W2     = (const float*)d_in[11];
  const float* b2     = (const float*)d_in[12];
  float* out = (float*)d_out;

  float* w = (float*)d_ws;
  float* g0    = w;                        // 1024*256
  float* qlin0 = g0 + (size_t)BB * DD;     // 1024*256
  float* WkT   = qlin0 + (size_t)BB * DD;  // 256*256
  float* M1    = WkT + DD * DD;            // 256*256
  float* M2    = M1 + DD * DD;             // 256*256
  float* qws0  = M2 + DD * DD;             // 256

  k_mean<<<BB, 256, 0, stream>>>(E, g0);
  k_transpose<<<64, 256, 0, stream>>>(Wk, WkT);
  k_gemm<<<dim3(8, 8), 256, 0, stream>>>(Wo, Wc, M1, 256, 256, 256, 0);
  k_gemm<<<dim3(8, 8), 256, 0, stream>>>(Wo, Wlk, M2, 256, 256, 256, 1);
  k_gemm<<<dim3(8, 32), 256, 0, stream>>>(g0, Wc, qlin0, 1024, 256, 256, 0);
  k_qws0<<<1, 256, 0, stream>>>(Wph, Ws, qws0);
  k_decode<<<256, 1024, 0, stream>>>(E, coords, Ws, W1, b1, W2, b2, WkT, Wv,
                                     M1, M2, qws0, qlin0, out);
}